// Round 7
// baseline (453.265 us; speedup 1.0000x reference)
//
#include <hip/hip_runtime.h>
#include <math.h>

#define Nn 512
#define Mm 32000
#define Bb 64
#define Tt 256
#define NCONS 4     // consumer (recursion) blocks
#define NPROD 128   // producer (emission) blocks

typedef float v4f __attribute__((ext_vector_type(4)));
typedef float f4  __attribute__((ext_vector_type(4)));
typedef int   v4i __attribute__((ext_vector_type(4)));
typedef int   v8i __attribute__((ext_vector_type(8)));

// pack 4 f32 -> 4 OCP e4m3 bytes in an int
__device__ inline int pk4fp8(float a, float b, float c, float d) {
  int r = __builtin_amdgcn_cvt_pk_fp8_f32(a, b, 0, false);
  r = __builtin_amdgcn_cvt_pk_fp8_f32(c, d, r, true);
  return r;
}

// ---- single fused kernel: blocks 0-3 recursion consumers, 4-131 producers ----
// progress[0..7]: Pem2 32-step chunks (count to NPROD); progress[8]: colsum done (count to 32)
__global__ __launch_bounds__(512, 1) void k_all(
    const float* __restrict__ trans, const float* __restrict__ emis,
    const int* __restrict__ x, const float* __restrict__ prior,
    const int* __restrict__ Tlen, float* __restrict__ colsum,
    float* __restrict__ Pem2, int* __restrict__ progress, float* __restrict__ out)
{
  __shared__ __align__(16) char ybuf[2][16 * Nn];   // fp8 Y [c][k], XOR-swizzled; 16 KB
  __shared__ __align__(16) float Spart[2][16][12];  // [c][w] column-sum partials
  __shared__ __align__(16) float ss[512];
  __shared__ __align__(16) f4 ss4[512];
  __shared__ char pad_[60 * 1024];                  // push LDS > 80KB -> 1 block/CU
  const int tid = threadIdx.x;
  if ((int)blockIdx.x == -1) ((volatile char*)pad_)[tid] = 1;  // keep pad_ alive

  if (blockIdx.x >= NCONS) {
    // ================= producer =================
    const int p = blockIdx.x - NCONS;      // j-quad p -> emis rows 4p..4p+3
    const int j0 = p * 4;

    // phase A (p<32 only): colsum[k] += sum of 16 rows of exp(trans), then publish
    if (p < 32) {
      float a = 0.f;
      #pragma unroll 4
      for (int r = 0; r < 16; ++r)
        a += __expf(trans[(p * 16 + r) * Nn + tid]);
      atomicAdd(&colsum[tid], a);
      __syncthreads();                     // drain all lanes' atomics
      if (tid == 0) {
        __builtin_amdgcn_fence(__ATOMIC_RELEASE, "agent");
        __hip_atomic_fetch_add(&progress[8], 1, __ATOMIC_RELAXED, __HIP_MEMORY_SCOPE_AGENT);
      }
    }

    // ptot = sum exp(prior)
    float e = __expf(prior[tid]);
    ss[tid] = e; __syncthreads();
    for (int off = 256; off; off >>= 1) { if (tid < off) ss[tid] += ss[tid + off]; __syncthreads(); }
    const float ptot = ss[0];

    // single-pass interleaved row-sums for the 4 rows
    const f4* q0 = (const f4*)(emis + (size_t)(j0 + 0) * Mm);
    const f4* q1 = (const f4*)(emis + (size_t)(j0 + 1) * Mm);
    const f4* q2 = (const f4*)(emis + (size_t)(j0 + 2) * Mm);
    const f4* q3 = (const f4*)(emis + (size_t)(j0 + 3) * Mm);
    f4 a4 = {0.f, 0.f, 0.f, 0.f};
    for (int i = tid; i < Mm / 4; i += 512) {
      f4 v0 = q0[i], v1 = q1[i], v2 = q2[i], v3 = q3[i];
      a4[0] += (__expf(v0[0]) + __expf(v0[1])) + (__expf(v0[2]) + __expf(v0[3]));
      a4[1] += (__expf(v1[0]) + __expf(v1[1])) + (__expf(v1[2]) + __expf(v1[3]));
      a4[2] += (__expf(v2[0]) + __expf(v2[1])) + (__expf(v2[2]) + __expf(v2[3]));
      a4[3] += (__expf(v3[0]) + __expf(v3[1])) + (__expf(v3[2]) + __expf(v3[3]));
    }
    ss4[tid] = a4; __syncthreads();
    for (int off = 256; off; off >>= 1) { if (tid < off) ss4[tid] += ss4[tid + off]; __syncthreads(); }
    f4 tot = ss4[0];
    f4 rs, fz;
    #pragma unroll
    for (int q = 0; q < 4; ++q) {
      rs[q] = 32768.f / tot[q];                               // 2^15 scale
      fz[q] = rs[q] * 256.f * __expf(prior[j0 + q]) / ptot;   // t=0: * 2^8 * pi
    }

    // gather + publish in 32-timestep chunks
    const float* r0 = emis + (size_t)(j0 + 0) * Mm;
    const float* r1 = emis + (size_t)(j0 + 1) * Mm;
    const float* r2 = emis + (size_t)(j0 + 2) * Mm;
    const float* r3 = emis + (size_t)(j0 + 3) * Mm;
    f4* P4 = (f4*)Pem2;
    for (int c8 = 0; c8 < 8; ++c8) {
      #pragma unroll
      for (int r = 0; r < 4; ++r) {
        int idx = c8 * 2048 + r * 512 + tid;
        int t = idx >> 6, b = idx & 63;
        int mv = x[b * Tt + t];
        f4 fq = (t == 0) ? fz : rs;
        f4 o = { __expf(r0[mv]) * fq[0], __expf(r1[mv]) * fq[1],
                 __expf(r2[mv]) * fq[2], __expf(r3[mv]) * fq[3] };
        P4[t * 8192 + (b >> 4) * 2048 + p * 16 + (b & 15)] = o;
      }
      __syncthreads();
      if (tid == 0) {
        __builtin_amdgcn_fence(__ATOMIC_RELEASE, "agent");
        __hip_atomic_fetch_add(&progress[c8], 1, __ATOMIC_RELAXED, __HIP_MEMORY_SCOPE_AGENT);
      }
    }
    return;
  }

  // ================= consumer: recursion on 16 batch cols =================
  const int g = blockIdx.x;
  const int w = tid >> 6, lane = tid & 63;
  const int c = lane & 15, kq = lane >> 4;
  const int jw = w * 64;
  const int swz = (c & 7) << 4;
  const int b = g * 16 + c;

  // wait for colsum, then build A fragments in-register from trans
  if (tid == 0) {
    while (__hip_atomic_load(&progress[8], __ATOMIC_RELAXED, __HIP_MEMORY_SCOPE_AGENT) < 32)
      __builtin_amdgcn_s_sleep(2);
  }
  __syncthreads();
  __builtin_amdgcn_fence(__ATOMIC_ACQUIRE, "agent");
  ss[tid] = 256.f / colsum[tid];           // staged inv-colsum (incl. 2^8 A-scale)
  __syncthreads();

  v8i af[4][4];                             // lane: A_s[jw+rt*16+c][kc*128+kq*32 .. +31]
  #pragma unroll
  for (int rt = 0; rt < 4; ++rt) {
    const float* trow = trans + (size_t)(jw + rt * 16 + c) * Nn;
    #pragma unroll
    for (int kc = 0; kc < 4; ++kc) {
      int k0 = kc * 128 + kq * 32;
      int wd[8];
      #pragma unroll
      for (int u = 0; u < 8; ++u) {
        f4 tv = *(const f4*)(trow + k0 + u * 4);
        f4 cw = *(const f4*)(&ss[k0 + u * 4]);   // kq-uniform -> LDS broadcast
        wd[u] = pk4fp8(__expf(tv[0]) * cw[0], __expf(tv[1]) * cw[1],
                       __expf(tv[2]) * cw[2], __expf(tv[3]) * cw[3]);
      }
      af[rt][kc] = (v8i){wd[0], wd[1], wd[2], wd[3], wd[4], wd[5], wd[6], wd[7]};
    }
  }

  const int Tb = Tlen[b];
  int E = 23;                               // Y = 2^E * alpha, exact integer bookkeeping
  int csafe = 0;

  #define ENSURE(NEED)                                                                      \
    while (csafe <= (NEED)) {                                                               \
      if (__hip_atomic_load(&progress[csafe], __ATOMIC_RELAXED,                             \
                            __HIP_MEMORY_SCOPE_AGENT) >= NPROD) {                           \
        ++csafe;                                                                            \
        __builtin_amdgcn_fence(__ATOMIC_ACQUIRE, "agent");                                  \
      } else __builtin_amdgcn_s_sleep(2);                                                   \
    }

  // hoisted swizzled LDS byte offsets
  int roA[4], roB[4], wof[4];
  #pragma unroll
  for (int kc = 0; kc < 4; ++kc) {
    int base = c * Nn + kc * 128 + kq * 32;
    roA[kc] = base ^ swz;
    roB[kc] = (base + 16) ^ swz;
  }
  #pragma unroll
  for (int rt = 0; rt < 4; ++rt)
    wof[rt] = (c * Nn + jw + rt * 16 + kq * 4) ^ swz;
  char* const yb0 = &ybuf[0][0];

  if (tid < 192) ((float*)&Spart[0][0][0])[tid] = 0.f;
  __syncthreads();

  ENSURE(0);                                // Pem2 chunk 0 ready

  // init: Y0 = Pem2[0] (includes 2^23 * pi * emprob)
  {
    int cc = tid & 15, grp = tid >> 4, jb = grp * 16, sz = (cc & 7) << 4;
    const f4* P0 = (const f4*)Pem2 + g * 2048 + (jb >> 2) * 16 + cc;
    float psum = 0.f;
    #pragma unroll
    for (int q = 0; q < 4; ++q) {
      f4 v = P0[q * 16];
      psum += (v[0] + v[1]) + (v[2] + v[3]);
      *reinterpret_cast<int*>(yb0 + ((cc * Nn + jb + q * 4) ^ sz)) = pk4fp8(v[0], v[1], v[2], v[3]);
    }
    atomicAdd(&Spart[0][cc][grp & 7], psum);
  }
  __syncthreads();

  const f4* PB = (const f4*)Pem2;
  #define PIDX(T, RT) ((T) * 8192 + g * 2048 + ((jw + (RT) * 16) >> 2) * 16 + kq * 16 + c)
  f4 pem[4];
  #pragma unroll
  for (int rt = 0; rt < 4; ++rt) pem[rt] = PB[PIDX(1, rt)];

  int pp = 0;                               // LDS buffer byte toggle (0/8192)
  for (int t = 1; t <= Tt; ++t) {
    int sp = pp >> 13;
    f4 s0 = *reinterpret_cast<const f4*>(&Spart[sp][c][0]);
    f4 s1 = *reinterpret_cast<const f4*>(&Spart[sp][c][4]);
    f4 st = s0 + s1;
    float S = (st[0] + st[1]) + (st[2] + st[3]);
    int expb = (int)((__float_as_uint(S) >> 23) & 0xFF);
    if (w == 0 && kq == 0 && Tb == t) out[b] = __logf(S) - (float)E * 0.69314718056f;
    if (t == Tt) break;
    E += 150 - expb;                        // E += 23 - ilogb(S)
    float scl = __uint_as_float((unsigned)(254 - expb) << 23);   // 2^-ilogb(S)

    bool pf = (t + 1 < Tt);
    if (pf && (((t + 1) & 31) == 0)) ENSURE((t + 1) >> 5);
    f4 pemN[4];
    if (pf) {
      #pragma unroll
      for (int rt = 0; rt < 4; ++rt) pemN[rt] = PB[PIDX(t + 1, rt)];
    }

    // B fragments from LDS (fp8, swizzled)
    const char* rp = yb0 + pp;
    union BU { v8i v; v4i h[2]; };
    BU bu[4];
    #pragma unroll
    for (int kc = 0; kc < 4; ++kc) {
      bu[kc].h[0] = *reinterpret_cast<const v4i*>(rp + roA[kc]);
      bu[kc].h[1] = *reinterpret_cast<const v4i*>(rp + roB[kc]);
    }

    v4f a0 = {0.f,0.f,0.f,0.f}, a1 = {0.f,0.f,0.f,0.f};
    v4f a2 = {0.f,0.f,0.f,0.f}, a3 = {0.f,0.f,0.f,0.f};
    #pragma unroll
    for (int kc = 0; kc < 4; ++kc) {
      v8i bbv = bu[kc].v;
      a0 = __builtin_amdgcn_mfma_scale_f32_16x16x128_f8f6f4(af[0][kc], bbv, a0, 0, 0, 0, 0x7F, 0, 0x7F);
      a1 = __builtin_amdgcn_mfma_scale_f32_16x16x128_f8f6f4(af[1][kc], bbv, a1, 0, 0, 0, 0x7F, 0, 0x7F);
      a2 = __builtin_amdgcn_mfma_scale_f32_16x16x128_f8f6f4(af[2][kc], bbv, a2, 0, 0, 0, 0x7F, 0, 0x7F);
      a3 = __builtin_amdgcn_mfma_scale_f32_16x16x128_f8f6f4(af[3][kc], bbv, a3, 0, 0, 0, 0x7F, 0, 0x7F);
    }

    // epilogue (packed f32 math): Y_t = acc .* pem .* 2^-e
    v4f scl4 = {scl, scl, scl, scl};
    char* wp = yb0 + (pp ^ 8192);
    f4 vs4 = {0.f, 0.f, 0.f, 0.f};
    #define EPI(AC, RT) {                                   \
      v4f vv = AC * (pem[RT] * scl4);                       \
      vs4 += vv;                                            \
      *reinterpret_cast<int*>(wp + wof[RT]) = pk4fp8(vv[0], vv[1], vv[2], vv[3]); }
    EPI(a0, 0) EPI(a1, 1) EPI(a2, 2) EPI(a3, 3)
    #undef EPI

    float vsum = (vs4[0] + vs4[1]) + (vs4[2] + vs4[3]);
    vsum += __shfl_xor(vsum, 16);
    vsum += __shfl_xor(vsum, 32);
    if (kq == 0) Spart[sp ^ 1][c][w] = vsum;

    if (pf) {
      #pragma unroll
      for (int rt = 0; rt < 4; ++rt) pem[rt] = pemN[rt];
    }
    pp ^= 8192;
    __syncthreads();
  }
  #undef PIDX
  #undef ENSURE
}

extern "C" void kernel_launch(void* const* d_in, const int* in_sizes, int n_in,
                              void* d_out, int out_size, void* d_ws, size_t ws_size,
                              hipStream_t stream) {
  const int*   x     = (const int*)  d_in[0];
  const int*   Tlen  = (const int*)  d_in[1];
  const float* trans = (const float*)d_in[2];
  const float* emis  = (const float*)d_in[3];
  const float* prior = (const float*)d_in[4];
  float* out = (float*)d_out;

  char* w = (char*)d_ws;
  float* colsum   = (float*)(w + (512 << 10));         // 2 KB
  int*   progress = (int*)  (w + (512 << 10) + 4096);  // 9 counters
  float* Pem2     = (float*)(w + (1024 << 10));        // 32 MB Pem2[t][g][j>>2][c][j&3]

  hipMemsetAsync(w + (512 << 10), 0, 8192, stream);    // colsum + progress
  k_all<<<NCONS + NPROD, 512, 0, stream>>>(trans, emis, x, prior, Tlen,
                                           colsum, Pem2, progress, out);
}

// Round 9
// 351.882 us; speedup vs baseline: 1.2881x; 1.2881x over previous
//
#include <hip/hip_runtime.h>
#include <math.h>

#define Nn 512
#define Mm 32000
#define Bb 64
#define Tt 256
#define NCONS 4     // consumer (recursion) blocks, 1024 threads / 16 waves each
#define NPROD 128   // producer (emission) blocks

typedef float v4f __attribute__((ext_vector_type(4)));
typedef float f4  __attribute__((ext_vector_type(4)));
typedef int   v4i __attribute__((ext_vector_type(4)));
typedef int   v8i __attribute__((ext_vector_type(8)));

// pack 4 f32 -> 4 OCP e4m3 bytes in an int
__device__ inline int pk4fp8(float a, float b, float c, float d) {
  int r = __builtin_amdgcn_cvt_pk_fp8_f32(a, b, 0, false);
  r = __builtin_amdgcn_cvt_pk_fp8_f32(c, d, r, true);
  return r;
}

// ---- colsum[k] = sum_j exp(trans[j][k]) ----
__global__ void k_colsum(const float* __restrict__ trans, float* __restrict__ colsum) {
  int tid = threadIdx.x;
  int j0 = blockIdx.x * 16;
  float a0 = 0.f, a1 = 0.f;
  for (int r = 0; r < 16; ++r) {
    a0 += __expf(trans[(j0 + r) * Nn + tid]);
    a1 += __expf(trans[(j0 + r) * Nn + 256 + tid]);
  }
  atomicAdd(&colsum[tid], a0);
  atomicAdd(&colsum[256 + tid], a1);
}

// ---- A_s[j][k] = 256*exp(trans[j][k])/colsum[k] as e4m3 ----
__global__ void k_writeA8(const float* __restrict__ trans, const float* __restrict__ colsum,
                          int* __restrict__ A8) {
  int d = blockIdx.x * 256 + threadIdx.x;
  int j = d >> 7, k0 = (d & 127) << 2;
  float v0 = 256.f * __expf(trans[j * Nn + k0 + 0]) / colsum[k0 + 0];
  float v1 = 256.f * __expf(trans[j * Nn + k0 + 1]) / colsum[k0 + 1];
  float v2 = 256.f * __expf(trans[j * Nn + k0 + 2]) / colsum[k0 + 2];
  float v3 = 256.f * __expf(trans[j * Nn + k0 + 3]) / colsum[k0 + 3];
  A8[d] = pk4fp8(v0, v1, v2, v3);
}

// ---- fused: blocks 0-3 recursion consumers (16 waves), 4-131 producers ----
// progress[0..7]: Pem2 32-step chunks (count to NPROD)
__global__ __launch_bounds__(1024, 4) void k_fused(
    const char* __restrict__ A8, const float* __restrict__ emis,
    const int* __restrict__ x, const float* __restrict__ prior,
    const int* __restrict__ Tlen, float* __restrict__ Pem2,
    int* __restrict__ progress, float* __restrict__ out)
{
  __shared__ __align__(16) char ybuf[2][16 * Nn];   // fp8 Y [c][k], XOR-swizzled; 16 KB
  __shared__ __align__(16) float Spart[2][16][20];  // [c][w] column-sum partials (padded)
  __shared__ __align__(16) float ss[1024];
  __shared__ __align__(16) f4 ss4[1024];
  const int tid = threadIdx.x;

  if (blockIdx.x >= NCONS) {
    // ================= producer: 4 emis rows, Pem2 in 32-t chunks =================
    const int p = blockIdx.x - NCONS;      // j-quad p -> emis rows 4p..4p+3
    const int j0 = p * 4;

    // ptot = sum exp(prior)
    float e = (tid < Nn) ? __expf(prior[tid]) : 0.f;
    ss[tid] = e; __syncthreads();
    for (int off = 512; off; off >>= 1) { if (tid < off) ss[tid] += ss[tid + off]; __syncthreads(); }
    const float ptot = ss[0];

    // single-pass interleaved row-sums for the 4 rows
    const f4* q0 = (const f4*)(emis + (size_t)(j0 + 0) * Mm);
    const f4* q1 = (const f4*)(emis + (size_t)(j0 + 1) * Mm);
    const f4* q2 = (const f4*)(emis + (size_t)(j0 + 2) * Mm);
    const f4* q3 = (const f4*)(emis + (size_t)(j0 + 3) * Mm);
    f4 a4 = {0.f, 0.f, 0.f, 0.f};
    for (int i = tid; i < Mm / 4; i += 1024) {
      f4 v0 = q0[i], v1 = q1[i], v2 = q2[i], v3 = q3[i];
      a4[0] += (__expf(v0[0]) + __expf(v0[1])) + (__expf(v0[2]) + __expf(v0[3]));
      a4[1] += (__expf(v1[0]) + __expf(v1[1])) + (__expf(v1[2]) + __expf(v1[3]));
      a4[2] += (__expf(v2[0]) + __expf(v2[1])) + (__expf(v2[2]) + __expf(v2[3]));
      a4[3] += (__expf(v3[0]) + __expf(v3[1])) + (__expf(v3[2]) + __expf(v3[3]));
    }
    ss4[tid] = a4; __syncthreads();
    for (int off = 512; off; off >>= 1) { if (tid < off) ss4[tid] += ss4[tid + off]; __syncthreads(); }
    f4 tot = ss4[0];
    f4 rs, fz;
    #pragma unroll
    for (int q = 0; q < 4; ++q) {
      rs[q] = 32768.f / tot[q];                               // 2^15 scale
      fz[q] = rs[q] * 256.f * __expf(prior[j0 + q]) / ptot;   // t=0: * 2^8 * pi
    }

    // gather + publish in 32-timestep chunks
    const float* r0 = emis + (size_t)(j0 + 0) * Mm;
    const float* r1 = emis + (size_t)(j0 + 1) * Mm;
    const float* r2 = emis + (size_t)(j0 + 2) * Mm;
    const float* r3 = emis + (size_t)(j0 + 3) * Mm;
    f4* P4 = (f4*)Pem2;
    for (int c8 = 0; c8 < 8; ++c8) {
      #pragma unroll
      for (int r = 0; r < 2; ++r) {
        int idx = c8 * 2048 + r * 1024 + tid;
        int t = idx >> 6, b = idx & 63;
        int mv = x[b * Tt + t];
        f4 fq = (t == 0) ? fz : rs;
        f4 o = { __expf(r0[mv]) * fq[0], __expf(r1[mv]) * fq[1],
                 __expf(r2[mv]) * fq[2], __expf(r3[mv]) * fq[3] };
        P4[t * 8192 + (b >> 4) * 2048 + p * 16 + (b & 15)] = o;
      }
      __syncthreads();
      if (tid == 0) {
        __builtin_amdgcn_fence(__ATOMIC_RELEASE, "agent");
        __hip_atomic_fetch_add(&progress[c8], 1, __ATOMIC_RELAXED, __HIP_MEMORY_SCOPE_AGENT);
      }
    }
    return;
  }

  // ================= consumer: 16 waves, 32 A-rows each =================
  const int g = blockIdx.x;
  const int w = tid >> 6, lane = tid & 63;
  const int c = lane & 15, kq = lane >> 4;
  const int jw = w * 32;                    // this wave's 32 A-rows
  const int swz = (c & 7) << 4;
  const int b = g * 16 + c;

  // A fragments (one-time, from A8): lane holds A_s[jw+rt*16+c][kc*128+kq*32 .. +31]
  v8i af[2][4];
  #pragma unroll
  for (int rt = 0; rt < 2; ++rt)
    #pragma unroll
    for (int kc = 0; kc < 4; ++kc)
      af[rt][kc] = *reinterpret_cast<const v8i*>(
          A8 + (size_t)(jw + rt * 16 + c) * Nn + kc * 128 + kq * 32);

  const int Tb = Tlen[b];
  int E = 23;                               // Y = 2^E * alpha
  int csafe = 0;

  #define ENSURE(NEED)                                                                      \
    while (csafe <= (NEED)) {                                                               \
      if (__hip_atomic_load(&progress[csafe], __ATOMIC_RELAXED,                             \
                            __HIP_MEMORY_SCOPE_AGENT) >= NPROD) {                           \
        ++csafe;                                                                            \
        __builtin_amdgcn_fence(__ATOMIC_ACQUIRE, "agent");                                  \
      } else __builtin_amdgcn_s_sleep(2);                                                   \
    }

  // LDS byte offsets: XOR identities verified (bit4 of bases = 0; kc*128 = bits>=7)
  const int roA0 = (c * Nn + kq * 32) ^ swz;        // + kc*128, ^16 for hi half
  const int roB0 = roA0 ^ 16;
  const int wof0 = (c * Nn + jw + kq * 4) ^ swz;    // ^16 for rt=1
  const int wof1 = wof0 ^ 16;
  char* const yb0 = &ybuf[0][0];

  if (tid < 640) ((float*)&Spart[0][0][0])[tid] = 0.f;
  __syncthreads();

  ENSURE(0);                                // Pem2 chunk 0 ready

  // init: Y0 = Pem2[0] (includes 2^23 * pi * emprob); 1024 threads, 8 rows each
  {
    int cc = tid & 15, grp = tid >> 4, jb = grp * 8, sz = (cc & 7) << 4;
    const f4* P0 = (const f4*)Pem2 + g * 2048 + (jb >> 2) * 16 + cc;
    float psum = 0.f;
    #pragma unroll
    for (int q = 0; q < 2; ++q) {
      f4 v = P0[q * 16];
      psum += (v[0] + v[1]) + (v[2] + v[3]);
      *reinterpret_cast<int*>(yb0 + ((cc * Nn + jb + q * 4) ^ sz)) = pk4fp8(v[0], v[1], v[2], v[3]);
    }
    atomicAdd(&Spart[0][cc][grp & 7], psum);
  }
  __syncthreads();

  const f4* PB = (const f4*)Pem2;
  #define PIDX(T, RT) ((T) * 8192 + g * 2048 + ((jw + (RT) * 16) >> 2) * 16 + kq * 16 + c)

  int pp = 0;                               // LDS buffer byte toggle (0/8192)
  for (int t = 1; t <= Tt; ++t) {
    // chunk-wait ONLY for t < Tt (t==Tt would ask for nonexistent chunk 8 -> deadlock)
    if (t < Tt && (t & 31) == 0) ENSURE(t >> 5);

    // emission probs for CURRENT t (hidden under MFMA issue below)
    f4 pem0, pem1;
    if (t < Tt) { pem0 = PB[PIDX(t, 0)]; pem1 = PB[PIDX(t, 1)]; }

    int sp = pp >> 13;
    f4 s0 = *reinterpret_cast<const f4*>(&Spart[sp][c][0]);
    f4 s1 = *reinterpret_cast<const f4*>(&Spart[sp][c][4]);
    f4 s2 = *reinterpret_cast<const f4*>(&Spart[sp][c][8]);
    f4 s3 = *reinterpret_cast<const f4*>(&Spart[sp][c][12]);
    f4 st = (s0 + s1) + (s2 + s3);
    float S = (st[0] + st[1]) + (st[2] + st[3]);
    int expb = (int)((__float_as_uint(S) >> 23) & 0xFF);
    if (w == 0 && kq == 0 && Tb == t) out[b] = __logf(S) - (float)E * 0.69314718056f;
    if (t == Tt) break;
    E += 150 - expb;                        // E += 23 - ilogb(S)
    float scl = __uint_as_float((unsigned)(254 - expb) << 23);   // 2^-ilogb(S)

    // B fragments streamed 2-at-a-time (reg diet for 4 waves/SIMD)
    const char* rp = yb0 + pp;
    v4f a0 = {0.f,0.f,0.f,0.f}, a1 = {0.f,0.f,0.f,0.f};
    union BU { v8i v; v4i h[2]; };
    BU bu0, bu1;
    bu0.h[0] = *reinterpret_cast<const v4i*>(rp + roA0);
    bu0.h[1] = *reinterpret_cast<const v4i*>(rp + roB0);
    bu1.h[0] = *reinterpret_cast<const v4i*>(rp + roA0 + 128);
    bu1.h[1] = *reinterpret_cast<const v4i*>(rp + roB0 + 128);
    a0 = __builtin_amdgcn_mfma_scale_f32_16x16x128_f8f6f4(af[0][0], bu0.v, a0, 0, 0, 0, 0x7F, 0, 0x7F);
    a1 = __builtin_amdgcn_mfma_scale_f32_16x16x128_f8f6f4(af[1][0], bu0.v, a1, 0, 0, 0, 0x7F, 0, 0x7F);
    a0 = __builtin_amdgcn_mfma_scale_f32_16x16x128_f8f6f4(af[0][1], bu1.v, a0, 0, 0, 0, 0x7F, 0, 0x7F);
    a1 = __builtin_amdgcn_mfma_scale_f32_16x16x128_f8f6f4(af[1][1], bu1.v, a1, 0, 0, 0, 0x7F, 0, 0x7F);
    bu0.h[0] = *reinterpret_cast<const v4i*>(rp + roA0 + 256);
    bu0.h[1] = *reinterpret_cast<const v4i*>(rp + roB0 + 256);
    bu1.h[0] = *reinterpret_cast<const v4i*>(rp + roA0 + 384);
    bu1.h[1] = *reinterpret_cast<const v4i*>(rp + roB0 + 384);
    a0 = __builtin_amdgcn_mfma_scale_f32_16x16x128_f8f6f4(af[0][2], bu0.v, a0, 0, 0, 0, 0x7F, 0, 0x7F);
    a1 = __builtin_amdgcn_mfma_scale_f32_16x16x128_f8f6f4(af[1][2], bu0.v, a1, 0, 0, 0, 0x7F, 0, 0x7F);
    a0 = __builtin_amdgcn_mfma_scale_f32_16x16x128_f8f6f4(af[0][3], bu1.v, a0, 0, 0, 0, 0x7F, 0, 0x7F);
    a1 = __builtin_amdgcn_mfma_scale_f32_16x16x128_f8f6f4(af[1][3], bu1.v, a1, 0, 0, 0, 0x7F, 0, 0x7F);

    // epilogue: Y_t = acc .* pem .* 2^-e
    v4f scl4 = {scl, scl, scl, scl};
    char* wp = yb0 + (pp ^ 8192);
    v4f v0 = a0 * (pem0 * scl4);
    v4f v1 = a1 * (pem1 * scl4);
    *reinterpret_cast<int*>(wp + wof0) = pk4fp8(v0[0], v0[1], v0[2], v0[3]);
    *reinterpret_cast<int*>(wp + wof1) = pk4fp8(v1[0], v1[1], v1[2], v1[3]);
    f4 vs4 = v0 + v1;
    float vsum = (vs4[0] + vs4[1]) + (vs4[2] + vs4[3]);
    vsum += __shfl_xor(vsum, 16);
    vsum += __shfl_xor(vsum, 32);
    if (kq == 0) Spart[sp ^ 1][c][w] = vsum;

    pp ^= 8192;
    __syncthreads();
  }
  #undef PIDX
  #undef ENSURE
}

extern "C" void kernel_launch(void* const* d_in, const int* in_sizes, int n_in,
                              void* d_out, int out_size, void* d_ws, size_t ws_size,
                              hipStream_t stream) {
  const int*   x     = (const int*)  d_in[0];
  const int*   Tlen  = (const int*)  d_in[1];
  const float* trans = (const float*)d_in[2];
  const float* emis  = (const float*)d_in[3];
  const float* prior = (const float*)d_in[4];
  float* out = (float*)d_out;

  char* w = (char*)d_ws;
  char*  A8       = (char*)(w);                        // 256 KB fp8 A_s[j][k]
  float* colsum   = (float*)(w + (512 << 10));         // 2 KB
  int*   progress = (int*)  (w + (512 << 10) + 4096);  // 8 chunk counters
  float* Pem2     = (float*)(w + (1024 << 10));        // 32 MB Pem2[t][g][j>>2][c][j&3]

  hipMemsetAsync(w + (512 << 10), 0, 8192, stream);    // colsum + progress
  k_colsum <<<32,  256, 0, stream>>>(trans, colsum);
  k_writeA8<<<256, 256, 0, stream>>>(trans, colsum, (int*)A8);
  k_fused  <<<NCONS + NPROD, 1024, 0, stream>>>(A8, emis, x, prior, Tlen, Pem2, progress, out);
}

// Round 10
// 351.406 us; speedup vs baseline: 1.2899x; 1.0014x over previous
//
#include <hip/hip_runtime.h>
#include <math.h>

#define Nn 512
#define Mm 32000
#define Bb 64
#define Tt 256
#define NCONS 4     // consumer (recursion) blocks, 1024 threads / 16 waves each
#define NPROD 128   // producer (emission) blocks

typedef float v4f __attribute__((ext_vector_type(4)));
typedef float f4  __attribute__((ext_vector_type(4)));
typedef int   v4i __attribute__((ext_vector_type(4)));
typedef int   v8i __attribute__((ext_vector_type(8)));

// pack 4 f32 -> 4 OCP e4m3 bytes in an int
__device__ inline int pk4fp8(float a, float b, float c, float d) {
  int r = __builtin_amdgcn_cvt_pk_fp8_f32(a, b, 0, false);
  r = __builtin_amdgcn_cvt_pk_fp8_f32(c, d, r, true);
  return r;
}

// ---- colsum[k] = sum_j exp(trans[j][k]) ----
__global__ void k_colsum(const float* __restrict__ trans, float* __restrict__ colsum) {
  int tid = threadIdx.x;
  int j0 = blockIdx.x * 16;
  float a0 = 0.f, a1 = 0.f;
  for (int r = 0; r < 16; ++r) {
    a0 += __expf(trans[(j0 + r) * Nn + tid]);
    a1 += __expf(trans[(j0 + r) * Nn + 256 + tid]);
  }
  atomicAdd(&colsum[tid], a0);
  atomicAdd(&colsum[256 + tid], a1);
}

// ---- A_s[j][k] = 256*exp(trans[j][k])/colsum[k] as e4m3 ----
__global__ void k_writeA8(const float* __restrict__ trans, const float* __restrict__ colsum,
                          int* __restrict__ A8) {
  int d = blockIdx.x * 256 + threadIdx.x;
  int j = d >> 7, k0 = (d & 127) << 2;
  float v0 = 256.f * __expf(trans[j * Nn + k0 + 0]) / colsum[k0 + 0];
  float v1 = 256.f * __expf(trans[j * Nn + k0 + 1]) / colsum[k0 + 1];
  float v2 = 256.f * __expf(trans[j * Nn + k0 + 2]) / colsum[k0 + 2];
  float v3 = 256.f * __expf(trans[j * Nn + k0 + 3]) / colsum[k0 + 3];
  A8[d] = pk4fp8(v0, v1, v2, v3);
}

// ---- fused: blocks 0-3 recursion consumers (16 waves), 4-131 producers ----
// progress[0..7]: Pem2 32-step chunks (count to NPROD)
__global__ __launch_bounds__(1024, 4) void k_fused(
    const char* __restrict__ A8, const float* __restrict__ emis,
    const int* __restrict__ x, const float* __restrict__ prior,
    const int* __restrict__ Tlen, float* __restrict__ Pem2,
    int* __restrict__ progress, float* __restrict__ out)
{
  __shared__ __align__(16) char ybuf[2][16 * Nn];   // fp8 Y [c][k], XOR-swizzled; 16 KB
  __shared__ __align__(16) float Spart[2][16][20];  // [c][w] column-sum partials (padded)
  __shared__ __align__(16) float ss[1024];
  __shared__ __align__(16) f4 ss4[1024];
  const int tid = threadIdx.x;

  if (blockIdx.x >= NCONS) {
    // ================= producer: 4 emis rows, Pem2 in 32-t chunks =================
    const int p = blockIdx.x - NCONS;      // j-quad p -> emis rows 4p..4p+3
    const int j0 = p * 4;

    // ptot = sum exp(prior)
    float e = (tid < Nn) ? __expf(prior[tid]) : 0.f;
    ss[tid] = e; __syncthreads();
    for (int off = 512; off; off >>= 1) { if (tid < off) ss[tid] += ss[tid + off]; __syncthreads(); }
    const float ptot = ss[0];

    // single-pass interleaved row-sums for the 4 rows
    const f4* q0 = (const f4*)(emis + (size_t)(j0 + 0) * Mm);
    const f4* q1 = (const f4*)(emis + (size_t)(j0 + 1) * Mm);
    const f4* q2 = (const f4*)(emis + (size_t)(j0 + 2) * Mm);
    const f4* q3 = (const f4*)(emis + (size_t)(j0 + 3) * Mm);
    f4 a4 = {0.f, 0.f, 0.f, 0.f};
    for (int i = tid; i < Mm / 4; i += 1024) {
      f4 v0 = q0[i], v1 = q1[i], v2 = q2[i], v3 = q3[i];
      a4[0] += (__expf(v0[0]) + __expf(v0[1])) + (__expf(v0[2]) + __expf(v0[3]));
      a4[1] += (__expf(v1[0]) + __expf(v1[1])) + (__expf(v1[2]) + __expf(v1[3]));
      a4[2] += (__expf(v2[0]) + __expf(v2[1])) + (__expf(v2[2]) + __expf(v2[3]));
      a4[3] += (__expf(v3[0]) + __expf(v3[1])) + (__expf(v3[2]) + __expf(v3[3]));
    }
    ss4[tid] = a4; __syncthreads();
    for (int off = 512; off; off >>= 1) { if (tid < off) ss4[tid] += ss4[tid + off]; __syncthreads(); }
    f4 tot = ss4[0];
    f4 rs, fz;
    #pragma unroll
    for (int q = 0; q < 4; ++q) {
      rs[q] = 32768.f / tot[q];                               // 2^15 scale
      fz[q] = rs[q] * 256.f * __expf(prior[j0 + q]) / ptot;   // t=0: * 2^8 * pi
    }

    // gather + publish in 32-timestep chunks
    const float* r0 = emis + (size_t)(j0 + 0) * Mm;
    const float* r1 = emis + (size_t)(j0 + 1) * Mm;
    const float* r2 = emis + (size_t)(j0 + 2) * Mm;
    const float* r3 = emis + (size_t)(j0 + 3) * Mm;
    f4* P4 = (f4*)Pem2;
    for (int c8 = 0; c8 < 8; ++c8) {
      #pragma unroll
      for (int r = 0; r < 2; ++r) {
        int idx = c8 * 2048 + r * 1024 + tid;
        int t = idx >> 6, b = idx & 63;
        int mv = x[b * Tt + t];
        f4 fq = (t == 0) ? fz : rs;
        f4 o = { __expf(r0[mv]) * fq[0], __expf(r1[mv]) * fq[1],
                 __expf(r2[mv]) * fq[2], __expf(r3[mv]) * fq[3] };
        P4[t * 8192 + (b >> 4) * 2048 + p * 16 + (b & 15)] = o;
      }
      __syncthreads();
      if (tid == 0) {
        __builtin_amdgcn_fence(__ATOMIC_RELEASE, "agent");
        __hip_atomic_fetch_add(&progress[c8], 1, __ATOMIC_RELAXED, __HIP_MEMORY_SCOPE_AGENT);
      }
    }
    return;
  }

  // ================= consumer: 16 waves, 32 A-rows each =================
  const int g = blockIdx.x;
  const int w = tid >> 6, lane = tid & 63;
  const int c = lane & 15, kq = lane >> 4;
  const int jw = w * 32;                    // this wave's 32 A-rows
  const int swz = (c & 7) << 4;
  const int b = g * 16 + c;

  // A fragments (one-time, from A8): lane holds A_s[jw+rt*16+c][kc*128+kq*32 .. +31]
  v8i af[2][4];
  #pragma unroll
  for (int rt = 0; rt < 2; ++rt)
    #pragma unroll
    for (int kc = 0; kc < 4; ++kc)
      af[rt][kc] = *reinterpret_cast<const v8i*>(
          A8 + (size_t)(jw + rt * 16 + c) * Nn + kc * 128 + kq * 32);

  // LAUNDER: make af defs opaque so LLVM cannot rematerialize (re-load) them
  // inside the loop. Round-9 counter evidence: VGPR_Count=60 < 64 needed ->
  // af was remat'd from L2 every step (~256KB/block/step). Force residency.
  #pragma unroll
  for (int rt = 0; rt < 2; ++rt)
    #pragma unroll
    for (int kc = 0; kc < 4; ++kc)
      asm volatile("" : "+v"(af[rt][kc]));

  const int Tb = Tlen[b];
  int E = 23;                               // Y = 2^E * alpha
  int csafe = 0;

  #define ENSURE(NEED)                                                                      \
    while (csafe <= (NEED)) {                                                               \
      if (__hip_atomic_load(&progress[csafe], __ATOMIC_RELAXED,                             \
                            __HIP_MEMORY_SCOPE_AGENT) >= NPROD) {                           \
        ++csafe;                                                                            \
        __builtin_amdgcn_fence(__ATOMIC_ACQUIRE, "agent");                                  \
      } else __builtin_amdgcn_s_sleep(2);                                                   \
    }

  // LDS byte offsets: XOR identities verified (bit4 of bases = 0; kc*128 = bits>=7)
  const int roA0 = (c * Nn + kq * 32) ^ swz;        // + kc*128, ^16 for hi half
  const int roB0 = roA0 ^ 16;
  const int wof0 = (c * Nn + jw + kq * 4) ^ swz;    // ^16 for rt=1
  const int wof1 = wof0 ^ 16;
  char* const yb0 = &ybuf[0][0];

  if (tid < 640) ((float*)&Spart[0][0][0])[tid] = 0.f;
  __syncthreads();

  ENSURE(0);                                // Pem2 chunk 0 ready

  // init: Y0 = Pem2[0] (includes 2^23 * pi * emprob); 1024 threads, 8 rows each
  {
    int cc = tid & 15, grp = tid >> 4, jb = grp * 8, sz = (cc & 7) << 4;
    const f4* P0 = (const f4*)Pem2 + g * 2048 + (jb >> 2) * 16 + cc;
    float psum = 0.f;
    #pragma unroll
    for (int q = 0; q < 2; ++q) {
      f4 v = P0[q * 16];
      psum += (v[0] + v[1]) + (v[2] + v[3]);
      *reinterpret_cast<int*>(yb0 + ((cc * Nn + jb + q * 4) ^ sz)) = pk4fp8(v[0], v[1], v[2], v[3]);
    }
    atomicAdd(&Spart[0][cc][grp & 7], psum);
  }
  __syncthreads();

  const f4* PB = (const f4*)Pem2;
  #define PIDX(T, RT) ((T) * 8192 + g * 2048 + ((jw + (RT) * 16) >> 2) * 16 + kq * 16 + c)

  int pp = 0;                               // LDS buffer byte toggle (0/8192)
  for (int t = 1; t <= Tt; ++t) {
    // chunk-wait ONLY for t < Tt (t==Tt would ask for nonexistent chunk 8 -> deadlock)
    if (t < Tt && (t & 31) == 0) ENSURE(t >> 5);

    // emission probs for CURRENT t (hidden under MFMA issue below)
    f4 pem0, pem1;
    if (t < Tt) { pem0 = PB[PIDX(t, 0)]; pem1 = PB[PIDX(t, 1)]; }

    int sp = pp >> 13;
    f4 s0 = *reinterpret_cast<const f4*>(&Spart[sp][c][0]);
    f4 s1 = *reinterpret_cast<const f4*>(&Spart[sp][c][4]);
    f4 s2 = *reinterpret_cast<const f4*>(&Spart[sp][c][8]);
    f4 s3 = *reinterpret_cast<const f4*>(&Spart[sp][c][12]);
    f4 st = (s0 + s1) + (s2 + s3);
    float S = (st[0] + st[1]) + (st[2] + st[3]);
    int expb = (int)((__float_as_uint(S) >> 23) & 0xFF);
    if (w == 0 && kq == 0 && Tb == t) out[b] = __logf(S) - (float)E * 0.69314718056f;
    if (t == Tt) break;
    E += 150 - expb;                        // E += 23 - ilogb(S)
    float scl = __uint_as_float((unsigned)(254 - expb) << 23);   // 2^-ilogb(S)

    // B fragments streamed 2-at-a-time (reg diet for 4 waves/SIMD)
    const char* rp = yb0 + pp;
    v4f a0 = {0.f,0.f,0.f,0.f}, a1 = {0.f,0.f,0.f,0.f};
    union BU { v8i v; v4i h[2]; };
    BU bu0, bu1;
    bu0.h[0] = *reinterpret_cast<const v4i*>(rp + roA0);
    bu0.h[1] = *reinterpret_cast<const v4i*>(rp + roB0);
    bu1.h[0] = *reinterpret_cast<const v4i*>(rp + roA0 + 128);
    bu1.h[1] = *reinterpret_cast<const v4i*>(rp + roB0 + 128);
    a0 = __builtin_amdgcn_mfma_scale_f32_16x16x128_f8f6f4(af[0][0], bu0.v, a0, 0, 0, 0, 0x7F, 0, 0x7F);
    a1 = __builtin_amdgcn_mfma_scale_f32_16x16x128_f8f6f4(af[1][0], bu0.v, a1, 0, 0, 0, 0x7F, 0, 0x7F);
    a0 = __builtin_amdgcn_mfma_scale_f32_16x16x128_f8f6f4(af[0][1], bu1.v, a0, 0, 0, 0, 0x7F, 0, 0x7F);
    a1 = __builtin_amdgcn_mfma_scale_f32_16x16x128_f8f6f4(af[1][1], bu1.v, a1, 0, 0, 0, 0x7F, 0, 0x7F);
    bu0.h[0] = *reinterpret_cast<const v4i*>(rp + roA0 + 256);
    bu0.h[1] = *reinterpret_cast<const v4i*>(rp + roB0 + 256);
    bu1.h[0] = *reinterpret_cast<const v4i*>(rp + roA0 + 384);
    bu1.h[1] = *reinterpret_cast<const v4i*>(rp + roB0 + 384);
    a0 = __builtin_amdgcn_mfma_scale_f32_16x16x128_f8f6f4(af[0][2], bu0.v, a0, 0, 0, 0, 0x7F, 0, 0x7F);
    a1 = __builtin_amdgcn_mfma_scale_f32_16x16x128_f8f6f4(af[1][2], bu0.v, a1, 0, 0, 0, 0x7F, 0, 0x7F);
    a0 = __builtin_amdgcn_mfma_scale_f32_16x16x128_f8f6f4(af[0][3], bu1.v, a0, 0, 0, 0, 0x7F, 0, 0x7F);
    a1 = __builtin_amdgcn_mfma_scale_f32_16x16x128_f8f6f4(af[1][3], bu1.v, a1, 0, 0, 0, 0x7F, 0, 0x7F);

    // epilogue: Y_t = acc .* pem .* 2^-e
    v4f scl4 = {scl, scl, scl, scl};
    char* wp = yb0 + (pp ^ 8192);
    v4f v0 = a0 * (pem0 * scl4);
    v4f v1 = a1 * (pem1 * scl4);
    *reinterpret_cast<int*>(wp + wof0) = pk4fp8(v0[0], v0[1], v0[2], v0[3]);
    *reinterpret_cast<int*>(wp + wof1) = pk4fp8(v1[0], v1[1], v1[2], v1[3]);
    f4 vs4 = v0 + v1;
    float vsum = (vs4[0] + vs4[1]) + (vs4[2] + vs4[3]);
    vsum += __shfl_xor(vsum, 16);
    vsum += __shfl_xor(vsum, 32);
    if (kq == 0) Spart[sp ^ 1][c][w] = vsum;

    pp ^= 8192;
    __syncthreads();
  }
  #undef PIDX
  #undef ENSURE
}

extern "C" void kernel_launch(void* const* d_in, const int* in_sizes, int n_in,
                              void* d_out, int out_size, void* d_ws, size_t ws_size,
                              hipStream_t stream) {
  const int*   x     = (const int*)  d_in[0];
  const int*   Tlen  = (const int*)  d_in[1];
  const float* trans = (const float*)d_in[2];
  const float* emis  = (const float*)d_in[3];
  const float* prior = (const float*)d_in[4];
  float* out = (float*)d_out;

  char* w = (char*)d_ws;
  char*  A8       = (char*)(w);                        // 256 KB fp8 A_s[j][k]
  float* colsum   = (float*)(w + (512 << 10));         // 2 KB
  int*   progress = (int*)  (w + (512 << 10) + 4096);  // 8 chunk counters
  float* Pem2     = (float*)(w + (1024 << 10));        // 32 MB Pem2[t][g][j>>2][c][j&3]

  hipMemsetAsync(w + (512 << 10), 0, 8192, stream);    // colsum + progress
  k_colsum <<<32,  256, 0, stream>>>(trans, colsum);
  k_writeA8<<<256, 256, 0, stream>>>(trans, colsum, (int*)A8);
  k_fused  <<<NCONS + NPROD, 1024, 0, stream>>>(A8, emis, x, prior, Tlen, Pem2, progress, out);
}

// Round 12
// 318.966 us; speedup vs baseline: 1.4210x; 1.1017x over previous
//
#include <hip/hip_runtime.h>
#include <math.h>

#define Nn 512
#define Mm 32000
#define Bb 64
#define Tt 256
#define NCONS 4     // consumer (recursion) blocks, 512 threads / 8 waves each
#define NPROD 128   // producer (emission) blocks

typedef float v4f __attribute__((ext_vector_type(4)));
typedef float f4  __attribute__((ext_vector_type(4)));
typedef int   v4i __attribute__((ext_vector_type(4)));
typedef int   v8i __attribute__((ext_vector_type(8)));

// pack 4 f32 -> 4 OCP e4m3 bytes in an int
__device__ inline int pk4fp8(float a, float b, float c, float d) {
  int r = __builtin_amdgcn_cvt_pk_fp8_f32(a, b, 0, false);
  r = __builtin_amdgcn_cvt_pk_fp8_f32(c, d, r, true);
  return r;
}

// ---- colsum[k] = sum_j exp(trans[j][k]) ----
__global__ void k_colsum(const float* __restrict__ trans, float* __restrict__ colsum) {
  int tid = threadIdx.x;
  int j0 = blockIdx.x * 16;
  float a0 = 0.f, a1 = 0.f;
  for (int r = 0; r < 16; ++r) {
    a0 += __expf(trans[(j0 + r) * Nn + tid]);
    a1 += __expf(trans[(j0 + r) * Nn + 256 + tid]);
  }
  atomicAdd(&colsum[tid], a0);
  atomicAdd(&colsum[256 + tid], a1);
}

// ---- A_s[j][k] = 256*exp(trans[j][k])/colsum[k] as e4m3 ----
__global__ void k_writeA8(const float* __restrict__ trans, const float* __restrict__ colsum,
                          int* __restrict__ A8) {
  int d = blockIdx.x * 256 + threadIdx.x;
  int j = d >> 7, k0 = (d & 127) << 2;
  float v0 = 256.f * __expf(trans[j * Nn + k0 + 0]) / colsum[k0 + 0];
  float v1 = 256.f * __expf(trans[j * Nn + k0 + 1]) / colsum[k0 + 1];
  float v2 = 256.f * __expf(trans[j * Nn + k0 + 2]) / colsum[k0 + 2];
  float v3 = 256.f * __expf(trans[j * Nn + k0 + 3]) / colsum[k0 + 3];
  A8[d] = pk4fp8(v0, v1, v2, v3);
}

// ---- fused: blocks 0-3 recursion consumers (8 waves, 64 A-rows/wave), 4-131 producers ----
// amdgpu_waves_per_eu(2,2): pin EXACTLY 2 waves/SIMD -> 256-VGPR budget, so the
// allocator cannot chase 4 waves/SIMD and sink/spill the 128-reg af array
// (rounds 3-10 all had VGPR_Count < 128 => A was NEVER register-resident).
__global__ __attribute__((amdgpu_flat_work_group_size(512, 512), amdgpu_waves_per_eu(2, 2)))
void k_fused(
    const char* __restrict__ A8, const float* __restrict__ emis,
    const int* __restrict__ x, const float* __restrict__ prior,
    const int* __restrict__ Tlen, float* __restrict__ Pem2,
    int* __restrict__ progress, float* __restrict__ out)
{
  __shared__ __align__(16) char ybuf[2][16 * Nn];   // fp8 Y [c][k], XOR-swizzled; 16 KB
  __shared__ __align__(16) float Spart[2][16][12];  // [c][w] column-sum partials (padded)
  __shared__ __align__(16) float ss[512];
  __shared__ __align__(16) f4 ss4[512];
  const int tid = threadIdx.x;

  if (blockIdx.x >= NCONS) {
    // ================= producer: 4 emis rows, Pem2 in 32-t chunks =================
    const int p = blockIdx.x - NCONS;      // j-quad p -> emis rows 4p..4p+3
    const int j0 = p * 4;

    // ptot = sum exp(prior)  (512 threads == Nn)
    float e = __expf(prior[tid]);
    ss[tid] = e; __syncthreads();
    for (int off = 256; off; off >>= 1) { if (tid < off) ss[tid] += ss[tid + off]; __syncthreads(); }
    const float ptot = ss[0];

    // single-pass interleaved row-sums for the 4 rows
    const f4* q0 = (const f4*)(emis + (size_t)(j0 + 0) * Mm);
    const f4* q1 = (const f4*)(emis + (size_t)(j0 + 1) * Mm);
    const f4* q2 = (const f4*)(emis + (size_t)(j0 + 2) * Mm);
    const f4* q3 = (const f4*)(emis + (size_t)(j0 + 3) * Mm);
    f4 a4 = {0.f, 0.f, 0.f, 0.f};
    for (int i = tid; i < Mm / 4; i += 512) {
      f4 v0 = q0[i], v1 = q1[i], v2 = q2[i], v3 = q3[i];
      a4[0] += (__expf(v0[0]) + __expf(v0[1])) + (__expf(v0[2]) + __expf(v0[3]));
      a4[1] += (__expf(v1[0]) + __expf(v1[1])) + (__expf(v1[2]) + __expf(v1[3]));
      a4[2] += (__expf(v2[0]) + __expf(v2[1])) + (__expf(v2[2]) + __expf(v2[3]));
      a4[3] += (__expf(v3[0]) + __expf(v3[1])) + (__expf(v3[2]) + __expf(v3[3]));
    }
    ss4[tid] = a4; __syncthreads();
    for (int off = 256; off; off >>= 1) { if (tid < off) ss4[tid] += ss4[tid + off]; __syncthreads(); }
    f4 tot = ss4[0];
    f4 rs, fz;
    #pragma unroll
    for (int q = 0; q < 4; ++q) {
      rs[q] = 32768.f / tot[q];                               // 2^15 scale
      fz[q] = rs[q] * 256.f * __expf(prior[j0 + q]) / ptot;   // t=0: * 2^8 * pi
    }

    // gather + publish in 32-timestep chunks
    const float* r0 = emis + (size_t)(j0 + 0) * Mm;
    const float* r1 = emis + (size_t)(j0 + 1) * Mm;
    const float* r2 = emis + (size_t)(j0 + 2) * Mm;
    const float* r3 = emis + (size_t)(j0 + 3) * Mm;
    f4* P4 = (f4*)Pem2;
    for (int c8 = 0; c8 < 8; ++c8) {
      #pragma unroll
      for (int r = 0; r < 4; ++r) {
        int idx = c8 * 2048 + r * 512 + tid;
        int t = idx >> 6, b = idx & 63;
        int mv = x[b * Tt + t];
        f4 fq = (t == 0) ? fz : rs;
        f4 o = { __expf(r0[mv]) * fq[0], __expf(r1[mv]) * fq[1],
                 __expf(r2[mv]) * fq[2], __expf(r3[mv]) * fq[3] };
        P4[t * 8192 + (b >> 4) * 2048 + p * 16 + (b & 15)] = o;
      }
      __syncthreads();
      if (tid == 0) {
        __builtin_amdgcn_fence(__ATOMIC_RELEASE, "agent");
        __hip_atomic_fetch_add(&progress[c8], 1, __ATOMIC_RELAXED, __HIP_MEMORY_SCOPE_AGENT);
      }
    }
    return;
  }

  // ================= consumer: 8 waves, 64 A-rows each =================
  const int g = blockIdx.x;
  const int w = tid >> 6, lane = tid & 63;
  const int c = lane & 15, kq = lane >> 4;
  const int jw = w * 64;                    // this wave's 64 A-rows
  const int swz = (c & 7) << 4;
  const int b = g * 16 + c;

  // A fragments (one-time): lane holds A_s[jw+rt*16+c][kc*128+kq*32 .. +31]  (128 VGPRs)
  v8i af[4][4];
  #pragma unroll
  for (int rt = 0; rt < 4; ++rt)
    #pragma unroll
    for (int kc = 0; kc < 4; ++kc)
      af[rt][kc] = *reinterpret_cast<const v8i*>(
          A8 + (size_t)(jw + rt * 16 + c) * Nn + kc * 128 + kq * 32);

  // launder: block rematerialization/sinking of the af loads into the loop
  #pragma unroll
  for (int rt = 0; rt < 4; ++rt)
    #pragma unroll
    for (int kc = 0; kc < 4; ++kc)
      asm volatile("" : "+v"(af[rt][kc]));

  const int Tb = Tlen[b];
  int E = 23;                               // Y = 2^E * alpha
  int csafe = 0;

  #define ENSURE(NEED)                                                                      \
    while (csafe <= (NEED)) {                                                               \
      if (__hip_atomic_load(&progress[csafe], __ATOMIC_RELAXED,                             \
                            __HIP_MEMORY_SCOPE_AGENT) >= NPROD) {                           \
        ++csafe;                                                                            \
        __builtin_amdgcn_fence(__ATOMIC_ACQUIRE, "agent");                                  \
      } else __builtin_amdgcn_s_sleep(2);                                                   \
    }

  // LDS byte offsets (XOR identities: kc*128 = bits>=7 disjoint from swz; base bit4,5 usage checked)
  const int roA0 = (c * Nn + kq * 32) ^ swz;        // + kc*128; ^16 for hi half
  const int roB0 = roA0 ^ 16;
  const int wf0 = (c * Nn + jw + kq * 4) ^ swz;     // base bits 4,5 = 0 -> ^ (rt<<4) == + rt*16
  const int wf1 = wf0 ^ 16, wf2 = wf0 ^ 32, wf3 = wf0 ^ 48;
  char* const yb0 = &ybuf[0][0];

  if (tid < 192) ((float*)&Spart[0][0][0])[tid] = 0.f;
  __syncthreads();

  ENSURE(0);                                // Pem2 chunk 0 ready

  // init: Y0 = Pem2[0] (includes 2^23 * pi * emprob); 512 threads, 16 rows each
  {
    int cc = tid & 15, grp = tid >> 4, jb = grp * 16, sz = (cc & 7) << 4;
    const f4* P0 = (const f4*)Pem2 + g * 2048 + (jb >> 2) * 16 + cc;
    float psum = 0.f;
    #pragma unroll
    for (int q = 0; q < 4; ++q) {
      f4 v = P0[q * 16];
      psum += (v[0] + v[1]) + (v[2] + v[3]);
      *reinterpret_cast<int*>(yb0 + ((cc * Nn + jb + q * 4) ^ sz)) = pk4fp8(v[0], v[1], v[2], v[3]);
    }
    atomicAdd(&Spart[0][cc][grp & 7], psum);
  }
  __syncthreads();

  const f4* PB = (const f4*)Pem2;
  #define PIDX(T, RT) ((T) * 8192 + g * 2048 + ((jw + (RT) * 16) >> 2) * 16 + kq * 16 + c)

  int pp = 0;                               // LDS buffer byte toggle (0/8192)
  for (int t = 1; t <= Tt; ++t) {
    // chunk-wait ONLY for t < Tt (t==Tt would wait on nonexistent chunk 8 -> deadlock)
    if (t < Tt && (t & 31) == 0) ENSURE(t >> 5);

    // emission probs for CURRENT t (latency hidden under MFMA phase)
    f4 pem0, pem1, pem2, pem3;
    if (t < Tt) {
      pem0 = PB[PIDX(t, 0)]; pem1 = PB[PIDX(t, 1)];
      pem2 = PB[PIDX(t, 2)]; pem3 = PB[PIDX(t, 3)];
    }

    int sp = pp >> 13;
    f4 s0 = *reinterpret_cast<const f4*>(&Spart[sp][c][0]);
    f4 s1 = *reinterpret_cast<const f4*>(&Spart[sp][c][4]);
    f4 st = s0 + s1;
    float S = (st[0] + st[1]) + (st[2] + st[3]);
    int expb = (int)((__float_as_uint(S) >> 23) & 0xFF);
    if (w == 0 && kq == 0 && Tb == t) out[b] = __logf(S) - (float)E * 0.69314718056f;
    if (t == Tt) break;
    E += 150 - expb;                        // E += 23 - ilogb(S)
    float scl = __uint_as_float((unsigned)(254 - expb) << 23);   // 2^-ilogb(S)

    // B fragments streamed 2-at-a-time; 16 MFMAs total
    const char* rp = yb0 + pp;
    v4f a0 = {0.f,0.f,0.f,0.f}, a1 = {0.f,0.f,0.f,0.f};
    v4f a2 = {0.f,0.f,0.f,0.f}, a3 = {0.f,0.f,0.f,0.f};
    union BU { v8i v; v4i h[2]; };
    BU bu0, bu1;
    bu0.h[0] = *reinterpret_cast<const v4i*>(rp + roA0);
    bu0.h[1] = *reinterpret_cast<const v4i*>(rp + roB0);
    bu1.h[0] = *reinterpret_cast<const v4i*>(rp + roA0 + 128);
    bu1.h[1] = *reinterpret_cast<const v4i*>(rp + roB0 + 128);
    a0 = __builtin_amdgcn_mfma_scale_f32_16x16x128_f8f6f4(af[0][0], bu0.v, a0, 0, 0, 0, 0x7F, 0, 0x7F);
    a1 = __builtin_amdgcn_mfma_scale_f32_16x16x128_f8f6f4(af[1][0], bu0.v, a1, 0, 0, 0, 0x7F, 0, 0x7F);
    a2 = __builtin_amdgcn_mfma_scale_f32_16x16x128_f8f6f4(af[2][0], bu0.v, a2, 0, 0, 0, 0x7F, 0, 0x7F);
    a3 = __builtin_amdgcn_mfma_scale_f32_16x16x128_f8f6f4(af[3][0], bu0.v, a3, 0, 0, 0, 0x7F, 0, 0x7F);
    a0 = __builtin_amdgcn_mfma_scale_f32_16x16x128_f8f6f4(af[0][1], bu1.v, a0, 0, 0, 0, 0x7F, 0, 0x7F);
    a1 = __builtin_amdgcn_mfma_scale_f32_16x16x128_f8f6f4(af[1][1], bu1.v, a1, 0, 0, 0, 0x7F, 0, 0x7F);
    a2 = __builtin_amdgcn_mfma_scale_f32_16x16x128_f8f6f4(af[2][1], bu1.v, a2, 0, 0, 0, 0x7F, 0, 0x7F);
    a3 = __builtin_amdgcn_mfma_scale_f32_16x16x128_f8f6f4(af[3][1], bu1.v, a3, 0, 0, 0, 0x7F, 0, 0x7F);
    bu0.h[0] = *reinterpret_cast<const v4i*>(rp + roA0 + 256);
    bu0.h[1] = *reinterpret_cast<const v4i*>(rp + roB0 + 256);
    bu1.h[0] = *reinterpret_cast<const v4i*>(rp + roA0 + 384);
    bu1.h[1] = *reinterpret_cast<const v4i*>(rp + roB0 + 384);
    a0 = __builtin_amdgcn_mfma_scale_f32_16x16x128_f8f6f4(af[0][2], bu0.v, a0, 0, 0, 0, 0x7F, 0, 0x7F);
    a1 = __builtin_amdgcn_mfma_scale_f32_16x16x128_f8f6f4(af[1][2], bu0.v, a1, 0, 0, 0, 0x7F, 0, 0x7F);
    a2 = __builtin_amdgcn_mfma_scale_f32_16x16x128_f8f6f4(af[2][2], bu0.v, a2, 0, 0, 0, 0x7F, 0, 0x7F);
    a3 = __builtin_amdgcn_mfma_scale_f32_16x16x128_f8f6f4(af[3][2], bu0.v, a3, 0, 0, 0, 0x7F, 0, 0x7F);
    a0 = __builtin_amdgcn_mfma_scale_f32_16x16x128_f8f6f4(af[0][3], bu1.v, a0, 0, 0, 0, 0x7F, 0, 0x7F);
    a1 = __builtin_amdgcn_mfma_scale_f32_16x16x128_f8f6f4(af[1][3], bu1.v, a1, 0, 0, 0, 0x7F, 0, 0x7F);
    a2 = __builtin_amdgcn_mfma_scale_f32_16x16x128_f8f6f4(af[2][3], bu1.v, a2, 0, 0, 0, 0x7F, 0, 0x7F);
    a3 = __builtin_amdgcn_mfma_scale_f32_16x16x128_f8f6f4(af[3][3], bu1.v, a3, 0, 0, 0, 0x7F, 0, 0x7F);

    // epilogue: Y_t = acc .* pem .* 2^-e
    v4f scl4 = {scl, scl, scl, scl};
    char* wp = yb0 + (pp ^ 8192);
    v4f v0 = a0 * (pem0 * scl4);
    v4f v1 = a1 * (pem1 * scl4);
    v4f v2 = a2 * (pem2 * scl4);
    v4f v3 = a3 * (pem3 * scl4);
    *reinterpret_cast<int*>(wp + wf0) = pk4fp8(v0[0], v0[1], v0[2], v0[3]);
    *reinterpret_cast<int*>(wp + wf1) = pk4fp8(v1[0], v1[1], v1[2], v1[3]);
    *reinterpret_cast<int*>(wp + wf2) = pk4fp8(v2[0], v2[1], v2[2], v2[3]);
    *reinterpret_cast<int*>(wp + wf3) = pk4fp8(v3[0], v3[1], v3[2], v3[3]);
    f4 vs4 = (v0 + v1) + (v2 + v3);
    float vsum = (vs4[0] + vs4[1]) + (vs4[2] + vs4[3]);
    vsum += __shfl_xor(vsum, 16);
    vsum += __shfl_xor(vsum, 32);
    if (kq == 0) Spart[sp ^ 1][c][w] = vsum;

    pp ^= 8192;
    __syncthreads();
  }
  #undef PIDX
  #undef ENSURE
}

extern "C" void kernel_launch(void* const* d_in, const int* in_sizes, int n_in,
                              void* d_out, int out_size, void* d_ws, size_t ws_size,
                              hipStream_t stream) {
  const int*   x     = (const int*)  d_in[0];
  const int*   Tlen  = (const int*)  d_in[1];
  const float* trans = (const float*)d_in[2];
  const float* emis  = (const float*)d_in[3];
  const float* prior = (const float*)d_in[4];
  float* out = (float*)d_out;

  char* w = (char*)d_ws;
  char*  A8       = (char*)(w);                        // 256 KB fp8 A_s[j][k]
  float* colsum   = (float*)(w + (512 << 10));         // 2 KB
  int*   progress = (int*)  (w + (512 << 10) + 4096);  // 8 chunk counters
  float* Pem2     = (float*)(w + (1024 << 10));        // 32 MB Pem2[t][g][j>>2][c][j&3]

  hipMemsetAsync(w + (512 << 10), 0, 8192, stream);    // colsum + progress
  k_colsum <<<32,  256, 0, stream>>>(trans, colsum);
  k_writeA8<<<256, 256, 0, stream>>>(trans, colsum, (int*)A8);
  k_fused  <<<NCONS + NPROD, 512, 0, stream>>>(A8, emis, x, prior, Tlen, Pem2, progress, out);
}